// Round 11
// baseline (146.572 us; speedup 1.0000x reference)
//
#include <hip/hip_runtime.h>

#define B_ 16
#define N_ 1024
#define F_ 16
#define E_ 12
#define H_ 4

// 32 blocks x 512 threads: block (side,b) owns 1024 tokens (2/thread).
// Folded weights: W1=Wqkv_s*W_in (36x16), W2=Wqkv_c*Wo_s (36x12), W3=W_out*Wo_c (3x12)
// -> xi and i2 never materialize; no LDS token staging at all.
// Single cross-block hop: y-block publishes cross moments + y-mean -> x-block.
// ws: psC[16][160] | ymean[16][3] | flags[16] u64
#define OFF_PC 0
#define OFF_YM 2560
#define OFF_FLAG 2608
#define TAG_C 0x51A7E0C5ull

// raw-weight staging offsets (inside red[], transient)
#define SW_WIN   0
#define SW_BIN   192
#define SW_WQKVS 204
#define SW_BQKVS 636
#define SW_WOS   672
#define SW_BOS   816
#define SW_WQKVC 828
#define SW_BQKVC 1260
#define SW_WOC   1296
#define SW_BOC   1440
#define SW_WOUT  1452
#define SW_BOUT  1488
#define SW_TOT   1491

// folded-weight offsets (swF)
#define FW1 0      // 36x16  rows: q 0-11 | k 12-23 | v 24-35
#define FB1 576    // 36
#define FW2 612    // 36x12  rows: q 0-11 | k 12-23 | v 24-35 (cross)
#define FB2 1044   // 36
#define FW3 1080   // 3x12
#define FB3 1116   // 3
#define F_TOT 1119

// moment layout per head (39 used, stride 40):
// [0:3]=Sum k | [3:9]=Sum kk (00,11,22,01,02,12) | [9:12]=Sum v
// [12:21]=Sum k_i v_c | [21:39]=Sum kk_pair v_c

__device__ __forceinline__ void data_store(float* p, float v) {
  __hip_atomic_store((unsigned*)p, __float_as_uint(v),
                     __ATOMIC_RELAXED, __HIP_MEMORY_SCOPE_AGENT);
}
__device__ __forceinline__ float data_load(const float* p) {
  unsigned u = __hip_atomic_load((const unsigned*)p,
                                 __ATOMIC_RELAXED, __HIP_MEMORY_SCOPE_AGENT);
  return __uint_as_float(u);
}
__device__ __forceinline__ void flag_set(unsigned long long* f, unsigned long long tag) {
  __hip_atomic_store(f, tag, __ATOMIC_RELAXED, __HIP_MEMORY_SCOPE_AGENT);
}
__device__ __forceinline__ void flag_wait(unsigned long long* f, unsigned long long tag) {
  while (__hip_atomic_load(f, __ATOMIC_RELAXED, __HIP_MEMORY_SCOPE_AGENT) != tag)
    __builtin_amdgcn_s_sleep(2);
  asm volatile("" ::: "memory");
}

__device__ __forceinline__ void mom_accum(float k0, float k1, float k2,
                                          float v0, float v1, float v2, float* m) {
  m[0]+=k0; m[1]+=k1; m[2]+=k2;
  float s00=k0*k0, s11=k1*k1, s22=k2*k2, s01=k0*k1, s02=k0*k2, s12=k1*k2;
  m[3]+=s00; m[4]+=s11; m[5]+=s22; m[6]+=s01; m[7]+=s02; m[8]+=s12;
  m[9]+=v0; m[10]+=v1; m[11]+=v2;
  m[12]+=k0*v0; m[13]+=k0*v1; m[14]+=k0*v2;
  m[15]+=k1*v0; m[16]+=k1*v1; m[17]+=k1*v2;
  m[18]+=k2*v0; m[19]+=k2*v1; m[20]+=k2*v2;
  m[21]+=s00*v0; m[22]+=s00*v1; m[23]+=s00*v2;
  m[24]+=s11*v0; m[25]+=s11*v1; m[26]+=s11*v2;
  m[27]+=s22*v0; m[28]+=s22*v1; m[29]+=s22*v2;
  m[30]+=s01*v0; m[31]+=s01*v1; m[32]+=s01*v2;
  m[33]+=s02*v0; m[34]+=s02*v1; m[35]+=s02*v2;
  m[36]+=s12*v0; m[37]+=s12*v1; m[38]+=s12*v2;
}

// dual-token eval: each mu element read ONCE for both tokens
__device__ __forceinline__ void attn_eval2(const float* __restrict__ mu,
                                           const float* pa, const float* pb,
                                           float* oa, float* ob) {
  float A0=pa[0],A1=pa[1],A2=pa[2], B0=pb[0],B1=pb[1],B2=pb[2];
  float a00=A0*A0, a11=A1*A1, a22=A2*A2, a01=A0*A1, a02=A0*A2, a12=A1*A2;
  float b00=B0*B0, b11=B1*B1, b22=B2*B2, b01=B0*B1, b02=B0*B2, b12=B1*B2;
  float da=(float)N_, db=(float)N_, w;
  w=mu[0]; da=fmaf(A0,w,da);  db=fmaf(B0,w,db);
  w=mu[1]; da=fmaf(A1,w,da);  db=fmaf(B1,w,db);
  w=mu[2]; da=fmaf(A2,w,da);  db=fmaf(B2,w,db);
  w=mu[3]; da=fmaf(a00,w,da); db=fmaf(b00,w,db);
  w=mu[4]; da=fmaf(a11,w,da); db=fmaf(b11,w,db);
  w=mu[5]; da=fmaf(a22,w,da); db=fmaf(b22,w,db);
  w=mu[6]; da=fmaf(a01,w,da); db=fmaf(b01,w,db);
  w=mu[7]; da=fmaf(a02,w,da); db=fmaf(b02,w,db);
  w=mu[8]; da=fmaf(a12,w,da); db=fmaf(b12,w,db);
  float ia = 1.0f/da, ib = 1.0f/db;
#pragma unroll
  for (int c = 0; c < 3; c++) {
    float na, nb; w=mu[9+c]; na=w; nb=w;
    w=mu[12+c]; na=fmaf(A0,w,na);  nb=fmaf(B0,w,nb);
    w=mu[15+c]; na=fmaf(A1,w,na);  nb=fmaf(B1,w,nb);
    w=mu[18+c]; na=fmaf(A2,w,na);  nb=fmaf(B2,w,nb);
    w=mu[21+c]; na=fmaf(a00,w,na); nb=fmaf(b00,w,nb);
    w=mu[24+c]; na=fmaf(a11,w,na); nb=fmaf(b11,w,nb);
    w=mu[27+c]; na=fmaf(a22,w,na); nb=fmaf(b22,w,nb);
    w=mu[30+c]; na=fmaf(a01,w,na); nb=fmaf(b01,w,nb);
    w=mu[33+c]; na=fmaf(a02,w,na); nb=fmaf(b02,w,nb);
    w=mu[36+c]; na=fmaf(a12,w,na); nb=fmaf(b12,w,nb);
    oa[c]=na*ia; ob[c]=nb*ib;
  }
}

__device__ __forceinline__ float mom_scale(int j) {
  return ((j >= 3 && j < 6) || (j >= 21 && j < 30)) ? 0.5f : 1.0f;
}

__global__ __launch_bounds__(512, 1)
void k_all(const float* __restrict__ xo, const float* __restrict__ yo,
           const float* __restrict__ W_in, const float* __restrict__ b_in,
           const float* __restrict__ Wqkv_s, const float* __restrict__ bqkv_s,
           const float* __restrict__ Wo_s, const float* __restrict__ bo_s,
           const float* __restrict__ Wqkv_c, const float* __restrict__ bqkv_c,
           const float* __restrict__ Wo_c, const float* __restrict__ bo_c,
           const float* __restrict__ W_out, const float* __restrict__ b_out,
           float* __restrict__ ws, float* __restrict__ out) {
  __shared__ float swF[F_TOT];        // folded weights
  __shared__ float red[32 * 184];     // 23.5 KB; doubles as raw-weight staging
  __shared__ float rawR[176];
  __shared__ float smu[160];
  __shared__ float dq[12];
  __shared__ float smuC[160];
  __shared__ float myY[3];
  __shared__ float sredK[8][15];
  __shared__ float sXf[12];

  float* psC = ws + OFF_PC;
  float* pYM = ws + OFF_YM;
  unsigned long long* flags = (unsigned long long*)(ws + OFF_FLAG);

  int tid = threadIdx.x;
  int blk = blockIdx.x;
  int side = blk >> 4;              // pair (b, 16+b): same XCD
  int b = blk & 15;
  int grp = tid >> 4;               // 32 groups of 16 lanes
  bool rep = (tid & 15) == 0;
  const float SC = 0.57735026918962584f;   // 1/sqrt(3)
  const float invN = 1.0f / N_;
  const float Nf = (float)N_;

  // ---- stage raw weights into red[] ----
  for (int i = tid; i < SW_TOT; i += 512) {
    float v;
    if (i < 192)       v = W_in[i];
    else if (i < 204)  v = b_in[i - 192];
    else if (i < 636)  v = Wqkv_s[i - 204];
    else if (i < 672)  v = bqkv_s[i - 636];
    else if (i < 816)  v = Wo_s[i - 672];
    else if (i < 828)  v = bo_s[i - 816];
    else if (i < 1260) v = Wqkv_c[i - 828];
    else if (i < 1296) v = bqkv_c[i - 1260];
    else if (i < 1440) v = Wo_c[i - 1296];
    else if (i < 1452) v = bo_c[i - 1440];
    else if (i < 1488) v = W_out[i - 1452];
    else               v = b_out[i - 1488];
    red[i] = v;
  }
  __syncthreads();
  // ---- fold: W1 = Wqkv_s*W_in, W2 = Wqkv_c*Wo_s, W3 = W_out*Wo_c (+biases) ----
  if (tid < 36) {
    int o = tid;
#pragma unroll
    for (int f = 0; f < F_; f++) {
      float s = 0.f;
#pragma unroll
      for (int e = 0; e < E_; e++)
        s = fmaf(red[SW_WQKVS + o*E_ + e], red[SW_WIN + e*F_ + f], s);
      swF[FW1 + o*F_ + f] = s;
    }
    float bs = red[SW_BQKVS + o];
#pragma unroll
    for (int e = 0; e < E_; e++)
      bs = fmaf(red[SW_WQKVS + o*E_ + e], red[SW_BIN + e], bs);
    swF[FB1 + o] = bs;
  } else if (tid < 72) {
    int o = tid - 36;
#pragma unroll
    for (int j = 0; j < E_; j++) {
      float s = 0.f;
#pragma unroll
      for (int e = 0; e < E_; e++)
        s = fmaf(red[SW_WQKVC + o*E_ + e], red[SW_WOS + e*E_ + j], s);
      swF[FW2 + o*E_ + j] = s;
    }
    float bs = red[SW_BQKVC + o];
#pragma unroll
    for (int e = 0; e < E_; e++)
      bs = fmaf(red[SW_WQKVC + o*E_ + e], red[SW_BOS + e], bs);
    swF[FB2 + o] = bs;
  } else if (tid < 75) {
    int k = tid - 72;
#pragma unroll
    for (int j = 0; j < E_; j++) {
      float s = 0.f;
#pragma unroll
      for (int e = 0; e < E_; e++)
        s = fmaf(red[SW_WOUT + k*E_ + e], red[SW_WOC + e*E_ + j], s);
      swF[FW3 + k*E_ + j] = s;
    }
    float bs = red[SW_BOUT + k];
#pragma unroll
    for (int e = 0; e < E_; e++)
      bs = fmaf(red[SW_WOUT + k*E_ + e], red[SW_BOC + e], bs);
    swF[FB3 + k] = bs;
  }
  const float* src = side ? yo : xo;

  // ---- load 2 tokens ----
  float xva[F_], xvb[F_];
  {
    const float4* pa = (const float4*)(src + ((size_t)b * N_ + tid) * F_);
    const float4* pb = (const float4*)(src + ((size_t)b * N_ + tid + 512) * F_);
#pragma unroll
    for (int q = 0; q < 4; q++) {
      float4 va = pa[q], vb = pb[q];
      xva[4*q+0]=va.x; xva[4*q+1]=va.y; xva[4*q+2]=va.z; xva[4*q+3]=va.w;
      xvb[4*q+0]=vb.x; xvb[4*q+1]=vb.y; xvb[4*q+2]=vb.z; xvb[4*q+3]=vb.w;
    }
  }
  float xra[3] = { xva[0], xva[1], xva[2] };
  float xrb[3] = { xvb[0], xvb[1], xvb[2] };
  __syncthreads();                  // folded weights ready; red now free

  // ================= Phase A: q (regs) + raw k/v moments + x-sums =================
  float qra[E_], qrb[E_];
#pragma unroll
  for (int o = 0; o < 12; o++) {
    const float* wr = &swF[FW1 + o*F_];
    float sa = swF[FB1 + o], sb = sa;
#pragma unroll
    for (int f = 0; f < F_; f++) { float we = wr[f]; sa=fmaf(xva[f],we,sa); sb=fmaf(xvb[f],we,sb); }
    qra[o]=sa; qrb[o]=sb;
  }
#pragma unroll
  for (int h = 0; h < H_; h++) {
    float m[40];
#pragma unroll
    for (int j = 0; j < 40; j++) m[j] = 0.f;
    float ka[6], kb[6];
#pragma unroll
    for (int d = 0; d < 6; d++) {
      int o = 12 + (d/3)*12 + h*3 + (d%3);
      const float* wr = &swF[FW1 + o*F_];
      float sa = swF[FB1 + o], sb = sa;
#pragma unroll
      for (int f = 0; f < F_; f++) { float we = wr[f]; sa=fmaf(xva[f],we,sa); sb=fmaf(xvb[f],we,sb); }
      ka[d]=sa; kb[d]=sb;
    }
    mom_accum(ka[0],ka[1],ka[2],ka[3],ka[4],ka[5], m);
    mom_accum(kb[0],kb[1],kb[2],kb[3],kb[4],kb[5], m);
#pragma unroll
    for (int j = 0; j < 39; j++) {
      m[j] += __shfl_xor(m[j], 1);
      m[j] += __shfl_xor(m[j], 2);
      m[j] += __shfl_xor(m[j], 4);
      m[j] += __shfl_xor(m[j], 8);
    }
    if (rep) {
#pragma unroll
      for (int j4 = 0; j4 < 10; j4++)
        *(float4*)&red[grp*184 + h*40 + j4*4] =
          make_float4(m[j4*4], m[j4*4+1], m[j4*4+2], m[j4*4+3]);
    }
  }
  {
    float xs[F_];
#pragma unroll
    for (int f = 0; f < F_; f++) {
      float v = xva[f] + xvb[f];
      v += __shfl_xor(v, 1);
      v += __shfl_xor(v, 2);
      v += __shfl_xor(v, 4);
      v += __shfl_xor(v, 8);
      xs[f] = v;
    }
    if (rep) {
#pragma unroll
      for (int j4 = 0; j4 < 4; j4++)
        *(float4*)&red[grp*184 + 160 + j4*4] =
          make_float4(xs[j4*4], xs[j4*4+1], xs[j4*4+2], xs[j4*4+3]);
    }
  }
  __syncthreads();
  if (tid < 176) {
    float a = 0.f;
#pragma unroll
    for (int g = 0; g < 32; g++) a += red[g*184 + tid];
    rawR[tid] = a;
  }
  __syncthreads();

  // ---- shifted-moment correction (own side), tid 0..3 = head; uses folded W1 ----
  if (tid < H_) {
    int h = tid;
    float mu[F_];
#pragma unroll
    for (int f = 0; f < F_; f++) mu[f] = rawR[160+f] * invN;
    float A[3], G[3];
#pragma unroll
    for (int d = 0; d < 3; d++) {
      float sq=0.f, sk=0.f, sv=0.f;
#pragma unroll
      for (int f = 0; f < F_; f++) {
        sq = fmaf(mu[f], swF[FW1 + (h*3+d)*F_ + f], sq);
        sk = fmaf(mu[f], swF[FW1 + (12 + h*3+d)*F_ + f], sk);
        sv = fmaf(mu[f], swF[FW1 + (24 + h*3+d)*F_ + f], sv);
      }
      dq[h*3+d] = sq; A[d] = sk; G[d] = sv;
    }
    const float* R = &rawR[h*40];
    float S[39];
#pragma unroll
    for (int i = 0; i < 3; i++) S[i] = R[i] - Nf*A[i];
    const int PI[6] = {0,1,2,0,0,1}, PJ[6] = {0,1,2,1,2,2};
#pragma unroll
    for (int p = 0; p < 6; p++) {
      int i = PI[p], j = PJ[p];
      S[3+p] = R[3+p] - A[i]*R[j] - A[j]*R[i] + Nf*A[i]*A[j];
    }
#pragma unroll
    for (int cc = 0; cc < 3; cc++) S[9+cc] = R[9+cc] - Nf*G[cc];
#pragma unroll
    for (int i = 0; i < 3; i++)
#pragma unroll
      for (int cc = 0; cc < 3; cc++)
        S[12+i*3+cc] = R[12+i*3+cc] - A[i]*R[9+cc] - G[cc]*R[i] + Nf*A[i]*G[cc];
#pragma unroll
    for (int p = 0; p < 6; p++) {
      int i = PI[p], j = PJ[p];
#pragma unroll
      for (int cc = 0; cc < 3; cc++) {
        S[21+p*3+cc] = R[21+p*3+cc]
                     - A[i]*R[12+j*3+cc] - A[j]*R[12+i*3+cc]
                     - G[cc]*R[3+p]
                     + A[i]*A[j]*R[9+cc]
                     + A[i]*G[cc]*R[j] + A[j]*G[cc]*R[i]
                     - Nf*A[i]*A[j]*G[cc];
      }
    }
#pragma unroll
    for (int j = 0; j < 39; j++) smu[h*40+j] = S[j] * mom_scale(j);
    smu[h*40+39] = 0.f;
  }
  __syncthreads();

  // ================= Phase B: self-attn -> (x: cross-q regs | y: cross moments) ======
  float ata[E_], atb[E_];
#pragma unroll
  for (int h = 0; h < H_; h++) {
    float pa[3] = { (qra[h*3+0]-dq[h*3+0])*SC, (qra[h*3+1]-dq[h*3+1])*SC, (qra[h*3+2]-dq[h*3+2])*SC };
    float pb[3] = { (qrb[h*3+0]-dq[h*3+0])*SC, (qrb[h*3+1]-dq[h*3+1])*SC, (qrb[h*3+2]-dq[h*3+2])*SC };
    attn_eval2(&smu[h*40], pa, pb, &ata[h*3], &atb[h*3]);
  }
  float qca[E_], qcb[E_];           // x: cross-q; y: unused
  if (!side) {
#pragma unroll
    for (int o = 0; o < 12; o++) {
      const float* wr = &swF[FW2 + o*E_];
      float sa = swF[FB2 + o], sb = sa;
#pragma unroll
      for (int e = 0; e < E_; e++) { float we = wr[e]; sa=fmaf(ata[e],we,sa); sb=fmaf(atb[e],we,sb); }
      qca[o]=sa; qcb[o]=sb;
    }
  } else {
#pragma unroll
    for (int h = 0; h < H_; h++) {
      float m[40];
#pragma unroll
      for (int j = 0; j < 40; j++) m[j] = 0.f;
      float ka[6], kb[6];
#pragma unroll
      for (int d = 0; d < 6; d++) {
        int o = 12 + (d/3)*12 + h*3 + (d%3);
        const float* wr = &swF[FW2 + o*E_];
        float sa = swF[FB2 + o], sb = sa;
#pragma unroll
        for (int e = 0; e < E_; e++) { float we = wr[e]; sa=fmaf(ata[e],we,sa); sb=fmaf(atb[e],we,sb); }
        ka[d]=sa; kb[d]=sb;
      }
      mom_accum(ka[0],ka[1],ka[2],ka[3],ka[4],ka[5], m);
      mom_accum(kb[0],kb[1],kb[2],kb[3],kb[4],kb[5], m);
#pragma unroll
      for (int j = 0; j < 39; j++) {
        m[j] += __shfl_xor(m[j], 1);
        m[j] += __shfl_xor(m[j], 2);
        m[j] += __shfl_xor(m[j], 4);
        m[j] += __shfl_xor(m[j], 8);
      }
      if (rep) {
#pragma unroll
        for (int j4 = 0; j4 < 10; j4++)
          *(float4*)&red[grp*184 + h*40 + j4*4] =
            make_float4(m[j4*4], m[j4*4+1], m[j4*4+2], m[j4*4+3]);
      }
    }
    __syncthreads();
    if (tid < 160) {
      float a = 0.f;
#pragma unroll
      for (int g = 0; g < 32; g++) a += red[g*184 + tid];
      data_store(&psC[(size_t)b*160 + tid], a);
    } else if (tid < 163) {
      data_store(&pYM[b*3 + (tid - 160)], rawR[160 + (tid - 160)]);
    }
    __syncthreads();                // drains vmcnt for all waves
    if (tid == 0) flag_set(&flags[b], TAG_C);
    return;                         // y block done
  }

  // ================= x: wait for y, load cross moments =================
  if (tid == 0) flag_wait(&flags[b], TAG_C);
  __syncthreads();
  if (tid < 160) {
    int j = tid - (tid/40)*40;
    smuC[tid] = data_load(&psC[(size_t)b*160 + tid]) * mom_scale(j);
  } else if (tid < 163) {
    myY[tid-160] = data_load(&pYM[b*3 + (tid-160)]) * invN;
  }
  __syncthreads();

  // ================= Phase C: cross-attn + Kabsch stats =================
  float mx0 = rawR[160]*invN, mx1 = rawR[161]*invN, mx2 = rawR[162]*invN;
  xra[0]-=mx0; xra[1]-=mx1; xra[2]-=mx2;
  xrb[0]-=mx0; xrb[1]-=mx1; xrb[2]-=mx2;
  {
    float st[15];
#pragma unroll
    for (int i = 0; i < 15; i++) st[i] = 0.f;
    float aca[E_], acb[E_];
#pragma unroll
    for (int h = 0; h < H_; h++) {
      float pa[3] = { qca[h*3+0]*SC, qca[h*3+1]*SC, qca[h*3+2]*SC };
      float pb[3] = { qcb[h*3+0]*SC, qcb[h*3+1]*SC, qcb[h*3+2]*SC };
      attn_eval2(&smuC[h*40], pa, pb, &aca[h*3], &acb[h*3]);
    }
    float coa[3], cob[3];
#pragma unroll
    for (int k = 0; k < 3; k++) {
      const float* wr = &swF[FW3 + k*E_];
      float sa = swF[FB3 + k], sb = sa;
#pragma unroll
      for (int e = 0; e < E_; e++) { float we = wr[e]; sa=fmaf(aca[e],we,sa); sb=fmaf(acb[e],we,sb); }
      coa[k]=sa; cob[k]=sb;
    }
    {
      float A0 = coa[0]+xra[0], A1 = coa[1]+xra[1], A2 = coa[2]+xra[2];
      st[0]+=coa[0]; st[1]+=coa[1]; st[2]+=coa[2];
      st[3]+=xra[0]; st[4]+=xra[1]; st[5]+=xra[2];
      st[6]=fmaf(xra[0],A0,st[6]);  st[7]=fmaf(xra[0],A1,st[7]);  st[8]=fmaf(xra[0],A2,st[8]);
      st[9]=fmaf(xra[1],A0,st[9]);  st[10]=fmaf(xra[1],A1,st[10]); st[11]=fmaf(xra[1],A2,st[11]);
      st[12]=fmaf(xra[2],A0,st[12]); st[13]=fmaf(xra[2],A1,st[13]); st[14]=fmaf(xra[2],A2,st[14]);
    }
    {
      float A0 = cob[0]+xrb[0], A1 = cob[1]+xrb[1], A2 = cob[2]+xrb[2];
      st[0]+=cob[0]; st[1]+=cob[1]; st[2]+=cob[2];
      st[3]+=xrb[0]; st[4]+=xrb[1]; st[5]+=xrb[2];
      st[6]=fmaf(xrb[0],A0,st[6]);  st[7]=fmaf(xrb[0],A1,st[7]);  st[8]=fmaf(xrb[0],A2,st[8]);
      st[9]=fmaf(xrb[1],A0,st[9]);  st[10]=fmaf(xrb[1],A1,st[10]); st[11]=fmaf(xrb[1],A2,st[11]);
      st[12]=fmaf(xrb[2],A0,st[12]); st[13]=fmaf(xrb[2],A1,st[13]); st[14]=fmaf(xrb[2],A2,st[14]);
    }
#pragma unroll
    for (int i = 0; i < 15; i++) {
      st[i] += __shfl_down(st[i], 32); st[i] += __shfl_down(st[i], 16);
      st[i] += __shfl_down(st[i], 8);  st[i] += __shfl_down(st[i], 4);
      st[i] += __shfl_down(st[i], 2);  st[i] += __shfl_down(st[i], 1);
    }
    if ((tid & 63) == 0) {
      int wv = tid >> 6;
#pragma unroll
      for (int i = 0; i < 15; i++) sredK[wv][i] = st[i];
    }
  }
  __syncthreads();

  // ================= Phase D: polar (wave 0) + transform =================
  if (tid < 64) {
    float s[15];
#pragma unroll
    for (int i = 0; i < 15; i++) {
      float a = 0.f;
#pragma unroll
      for (int w = 0; w < 8; w++) a += sredK[w][i];
      s[i] = a;
    }
    float cB[3] = { s[3]*invN, s[4]*invN, s[5]*invN };
    float cA[3] = { (s[0]+s[3])*invN, (s[1]+s[4])*invN, (s[2]+s[5])*invN };
    float X[9];
#pragma unroll
    for (int i = 0; i < 3; i++)
#pragma unroll
      for (int j = 0; j < 3; j++)
        X[i*3+j] = s[6 + i*3 + j] - Nf * cB[i] * cA[j];
    float fn = 0.f;
#pragma unroll
    for (int i = 0; i < 9; i++) fn += X[i]*X[i];
    float scl = rsqrtf(fn);
#pragma unroll
    for (int i = 0; i < 9; i++) X[i] *= scl;
    for (int it = 0; it < 24; it++) {
      float c00 =  X[4]*X[8]-X[5]*X[7];
      float c01 = -(X[3]*X[8]-X[5]*X[6]);
      float c02 =  X[3]*X[7]-X[4]*X[6];
      float c10 = -(X[1]*X[8]-X[2]*X[7]);
      float c11 =  X[0]*X[8]-X[2]*X[6];
      float c12_= -(X[0]*X[7]-X[1]*X[6]);
      float c20 =  X[1]*X[5]-X[2]*X[4];
      float c21 = -(X[0]*X[5]-X[2]*X[3]);
      float c22 =  X[0]*X[4]-X[1]*X[3];
      float det = X[0]*c00 + X[1]*c01 + X[2]*c02;
      float id = 0.5f / det;
      X[0]=0.5f*X[0]+c00*id; X[1]=0.5f*X[1]+c01*id; X[2]=0.5f*X[2]+c02*id;
      X[3]=0.5f*X[3]+c10*id; X[4]=0.5f*X[4]+c11*id; X[5]=0.5f*X[5]+c12_*id;
      X[6]=0.5f*X[6]+c20*id; X[7]=0.5f*X[7]+c21*id; X[8]=0.5f*X[8]+c22*id;
    }
    if (tid == 0) {
#pragma unroll
      for (int i = 0; i < 9; i++) sXf[i] = X[i];
#pragma unroll
      for (int k = 0; k < 3; k++)
        sXf[9+k] = cA[k] - (cB[0]*X[k] + cB[1]*X[3+k] + cB[2]*X[6+k]) + myY[k];
    }
  }
  __syncthreads();
  {
    float X0=sXf[0], X1=sXf[1], X2=sXf[2], X3=sXf[3], X4=sXf[4], X5=sXf[5],
          X6=sXf[6], X7=sXf[7], X8=sXf[8], t0=sXf[9], t1=sXf[10], t2=sXf[11];
    size_t ta = (size_t)b * N_ + tid;
    size_t tb = ta + 512;
    out[ta*3+0] = fmaf(xra[0], X0, fmaf(xra[1], X3, fmaf(xra[2], X6, t0)));
    out[ta*3+1] = fmaf(xra[0], X1, fmaf(xra[1], X4, fmaf(xra[2], X7, t1)));
    out[ta*3+2] = fmaf(xra[0], X2, fmaf(xra[1], X5, fmaf(xra[2], X8, t2)));
    out[tb*3+0] = fmaf(xrb[0], X0, fmaf(xrb[1], X3, fmaf(xrb[2], X6, t0)));
    out[tb*3+1] = fmaf(xrb[0], X1, fmaf(xrb[1], X4, fmaf(xrb[2], X7, t1)));
    out[tb*3+2] = fmaf(xrb[0], X2, fmaf(xrb[1], X5, fmaf(xrb[2], X8, t2)));
  }
}

extern "C" void kernel_launch(void* const* d_in, const int* in_sizes, int n_in,
                              void* d_out, int out_size, void* d_ws, size_t ws_size,
                              hipStream_t stream) {
  const float* x_orig = (const float*)d_in[0];
  const float* y_orig = (const float*)d_in[1];
  const float* W_in   = (const float*)d_in[2];
  const float* b_in   = (const float*)d_in[3];
  const float* Wqkv_s = (const float*)d_in[4];
  const float* bqkv_s = (const float*)d_in[5];
  const float* Wo_s   = (const float*)d_in[6];
  const float* bo_s   = (const float*)d_in[7];
  const float* Wqkv_c = (const float*)d_in[8];
  const float* bqkv_c = (const float*)d_in[9];
  const float* Wo_c   = (const float*)d_in[10];
  const float* bo_c   = (const float*)d_in[11];
  const float* W_out  = (const float*)d_in[12];
  const float* b_out  = (const float*)d_in[13];
  float* ws = (float*)d_ws;

  k_all<<<32, 512, 0, stream>>>(x_orig, y_orig, W_in, b_in, Wqkv_s, bqkv_s,
                                Wo_s, bo_s, Wqkv_c, bqkv_c, Wo_c, bo_c,
                                W_out, b_out, ws, (float*)d_out);
}